// Round 12
// baseline (559.262 us; speedup 1.0000x reference)
//
#include <hip/hip_runtime.h>
#include <hip/hip_bf16.h>
#include <math.h>

// ---------------- problem constants ----------------
constexpr int NN = 50000;   // nodes
constexpr int EE = 800000;  // edges

// ---------------- workspace layout (float offsets) ----------------
// f32 weights (written by wnorm)
constexpr int OFF_WT_NODE  = 0;        // [128][512] k-major: col groups 0:asrc+asub 1:adst-asub 2:pool 3:pool2
constexpr int OFF_WT_AMUL  = 65536;    // [128][128] k-major
constexpr int OFF_WT_FINAL = 81920;    // [384][128] k-major; k: 0-127 neigh, 128-255 neigh2, 256-383 self
constexpr int OFF_WT_MLP   = 131072;   // 2 x [128][128] k-major
constexpr int OFF_WAOUT    = 163840;   // [128]
constexpr int OFF_BE       = 163968;   // [128]
constexpr int OFF_BFIN     = 164096;   // [128]
constexpr int OFF_BAOUT    = 164224;   // [1] (pad 16)
// fp16 transposed weight tables ([o][k])
constexpr int OFF_WNODEBF  = 164240;               // 512*128 ushort = 32768 fl
constexpr int OFF_WFINBF   = OFF_WNODEBF + 32768;  // 128*384 ushort = 24576 fl
constexpr int OFF_WMLPBF   = OFF_WFINBF + 24576;   // 2*128*128 ushort = 16384 fl
constexpr int OFF_WAMULBF  = OFF_WMLPBF + 16384;   // (unused, layout keeper)
// big arrays
constexpr int OFF_FEATBF   = OFF_WAMULBF + 8192;   // [N][128] fp16
constexpr int OFF_SBF      = OFF_FEATBF + NN*64;   // region reused: edge fused weight table
constexpr int OFF_WEDGEBF  = OFF_SBF;              // packed fragments: [(t*3+slice)*4+kb][lane 64][8] fp16
constexpr int OFF_HBF      = OFF_SBF + NN*128;     // [N][256] fp16 INTERLEAVED: pos (c>>1)*4+(c&1)+grp*2
constexpr int OFF_SEV      = OFF_HBF + NN*128;     // [E] f32, dst-sorted e (scratch for scan blocksums pre-edge)
constexpr int OFF_NEIGHBF  = OFF_SEV + EE;         // (free — segreduce fused into final)
constexpr int OFF_STARTS   = OFF_NEIGHBF + NN*128; // [N+1] int (+pad)
constexpr int OFF_HIST     = OFF_STARTS + NN + 8;  // [N] int
constexpr int OFF_CURSOR   = OFF_HIST + NN;        // [N] int
constexpr int OFF_SSRCD    = OFF_CURSOR + NN;      // [E] int2 (src,dst sorted by dst)

constexpr int SCAN_NB = (NN + 255) / 256;          // 196 scan blocks

typedef __attribute__((ext_vector_type(8))) _Float16 f16x8;
typedef __attribute__((ext_vector_type(2))) _Float16 f16x2;
typedef __attribute__((ext_vector_type(2))) __fp16 fp16x2r;   // builtin cvt_pkrtz return type
typedef __attribute__((ext_vector_type(4))) float f32x4;

// ---------------- device helpers ----------------
// fast GELU (tanh form via sigmoid), log2e folded into polynomial, rcp instead of div.
__device__ __forceinline__ float gelu_f(float x) {
    float x2 = x * x;
    float w = x * fmaf(-0.1029448f, x2, -2.3022082f);
    return x * __builtin_amdgcn_rcpf(1.0f + __builtin_amdgcn_exp2f(w));
}
__device__ __forceinline__ float leaky_f(float x) {
    return x > 0.0f ? x : 0.2f * x;
}
// packed 2x f32 -> fp16x2 in one v_cvt_pkrtz_f16_f32
__device__ __forceinline__ unsigned pk_f16(float lo, float hi) {
    fp16x2r p = __builtin_amdgcn_cvt_pkrtz(lo, hi);
    return *reinterpret_cast<unsigned*>(&p);
}
__device__ __forceinline__ unsigned short f2h(float x) {
    fp16x2r p = __builtin_amdgcn_cvt_pkrtz(x, 0.0f);
    return *reinterpret_cast<unsigned short*>(&p);
}
// packed fp16 multiply: one v_pk_mul_f16
__device__ __forceinline__ unsigned mulpack_h(unsigned a, unsigned b) {
    f16x2 x = *reinterpret_cast<f16x2*>(&a);
    f16x2 y = *reinterpret_cast<f16x2*>(&b);
    f16x2 r = x * y;
    return *reinterpret_cast<unsigned*>(&r);
}
__device__ __forceinline__ float2 up2(unsigned u) {
    f16x2 p = *reinterpret_cast<f16x2*>(&u);
    return make_float2((float)p.x, (float)p.y);
}
__device__ __forceinline__ float block_sum128(float v, float* sbuf) {
    #pragma unroll
    for (int o = 32; o > 0; o >>= 1) v += __shfl_down(v, o, 64);
    int lane = threadIdx.x & 63, w = threadIdx.x >> 6;
    if (lane == 0) sbuf[w] = v;
    __syncthreads();
    float r = sbuf[0] + sbuf[1];
    __syncthreads();
    return r;
}

// ---------------- weight normalization (+ hist zero piggyback) ----------------
struct WnormArgs {
    const float *asrc_v, *asrc_g, *asrc_b;
    const float *adst_v, *adst_g, *adst_b;
    const float *asub_v, *asub_g, *asub_b;
    const float *amul_v, *amul_g, *amul_b;
    const float *aout_v, *aout_g, *aout_b;
    const float *pool_v, *pool_g, *pool_b;
    const float *pool2_v, *pool2_g, *pool2_b;
    const float *self_v, *self_g, *self_b;
    const float *neigh_v, *neigh_g, *neigh_b;
    const float *neigh2_v, *neigh2_g, *neigh2_b;
    const float *mlp_v, *mlp_g, *mlp_b;
    float* ws;
};

__global__ __launch_bounds__(128) void wnorm_kernel(WnormArgs a) {
    __shared__ float sbuf[2];
    int bid = blockIdx.x, i = threadIdx.x;
    float* ws = a.ws;
    int gid = bid * 128 + i;
    if (gid < NN) ((int*)(ws + OFF_HIST))[gid] = 0;   // fused hist_zero
    if (bid < 1280) {
        int o = bid & 127, grp = bid >> 7;
        const float *v1 = nullptr, *g1 = nullptr, *v2 = nullptr, *g2 = nullptr;
        float sgn2 = 1.0f; float* dst = nullptr; int stride = 0;
        switch (grp) {
            case 0: v1=a.asrc_v; g1=a.asrc_g; v2=a.asub_v; g2=a.asub_g; sgn2= 1.f; dst=ws+OFF_WT_NODE+o;        stride=512; break;
            case 1: v1=a.adst_v; g1=a.adst_g; v2=a.asub_v; g2=a.asub_g; sgn2=-1.f; dst=ws+OFF_WT_NODE+128+o;    stride=512; break;
            case 2: v1=a.pool_v;  g1=a.pool_g;  dst=ws+OFF_WT_NODE+256+o;          stride=512; break;
            case 3: v1=a.pool2_v; g1=a.pool2_g; dst=ws+OFF_WT_NODE+384+o;          stride=512; break;
            case 4: v1=a.amul_v;  g1=a.amul_g;  dst=ws+OFF_WT_AMUL+o;              stride=128; break;
            case 5: v1=a.neigh_v; g1=a.neigh_g; dst=ws+OFF_WT_FINAL+o;             stride=128; break;
            case 6: v1=a.neigh2_v;g1=a.neigh2_g;dst=ws+OFF_WT_FINAL+128*128+o;     stride=128; break;
            case 7: v1=a.self_v;  g1=a.self_g;  dst=ws+OFF_WT_FINAL+256*128+o;     stride=128; break;
            case 8: v1=a.mlp_v;        g1=a.mlp_g;     dst=ws+OFF_WT_MLP+o;        stride=128; break;
            case 9: v1=a.mlp_v+16384;  g1=a.mlp_g+128; dst=ws+OFF_WT_MLP+16384+o;  stride=128; break;
        }
        float x1 = v1[o*128 + i];
        float n1 = sqrtf(block_sum128(x1*x1, sbuf));
        float w = g1[o] * x1 / n1;
        if (v2) {
            float x2 = v2[o*128 + i];
            float n2 = sqrtf(block_sum128(x2*x2, sbuf));
            w += sgn2 * g2[o] * x2 / n2;
        }
        dst[i * stride] = w;
    } else {
        float v = a.aout_v[i];
        float n = sqrtf(block_sum128(v*v, sbuf));
        ws[OFF_WAOUT + i] = a.aout_g[0] * v / n;
        ws[OFF_BE + i]    = a.asrc_b[i] + a.adst_b[i] + a.asub_b[i] + a.amul_b[i];
        ws[OFF_BFIN + i]  = a.self_b[i] + a.neigh_b[i] + a.neigh2_b[i];
        if (i == 0) ws[OFF_BAOUT] = a.aout_b[0];
    }
}

// ---------------- weight tables -> fp16 (+ fused dst histogram); 768 blocks x 256 ----------------
__global__ __launch_bounds__(256) void convert_weights_kernel(const int* __restrict__ dst,
                                                              float* __restrict__ ws) {
    int idx = blockIdx.x * 256 + threadIdx.x;
    unsigned short* wnodebf = (unsigned short*)(ws + OFF_WNODEBF);
    unsigned short* wfinbf  = (unsigned short*)(ws + OFF_WFINBF);
    unsigned short* wmlpbf  = (unsigned short*)(ws + OFF_WMLPBF);
    unsigned short* wedgebf = (unsigned short*)(ws + OFF_WEDGEBF);
    if (idx < 65536) {                 // node: [k 128][n 512] -> [n][k]
        int k = idx >> 9, n = idx & 511;
        wnodebf[n * 128 + k] = f2h(ws[OFF_WT_NODE + k * 512 + n]);
    } else if (idx < 114688) {         // final: [k 384][o 128] -> [o][k]
        int i = idx - 65536, k = i >> 7, o = i & 127;
        wfinbf[o * 384 + k] = f2h(ws[OFF_WT_FINAL + k * 128 + o]);
    } else if (idx < 147456) {         // mlp: 2 x [k 128][o 128] -> [o][k]
        int i = idx - 114688, l = i >> 14, j = i & 16383, k = j >> 7, o = j & 127;
        wmlpbf[l * 16384 + o * 128 + k] = f2h(ws[OFF_WT_MLP + l * 16384 + k * 128 + o]);
    } else {
        // packed fused edge table: fragment id f = (t*3+slice)*4+kb; layout [f][lane 64][elem 8]
        int i = idx - 147456;              // [0, 49152)
        int elem = i & 7, f = i >> 3;
        int lane = f & 63, kb = (f >> 6) & 3, ts = f >> 8;   // ts in [0,24)
        int t = ts / 3, slice = ts - t * 3;
        int o = t * 16 + (lane & 15);
        int kk = kb * 32 + (lane >> 4) * 8 + elem;
        float v = (slice == 0) ? ws[OFF_WT_AMUL + kk * 128 + o]
                : (slice == 1) ? ws[OFF_WT_NODE + kk * 512 + o]
                               : ws[OFF_WT_NODE + kk * 512 + 128 + o];
        wedgebf[i] = f2h(v);
    }
    // fused dst histogram (hist zeroed by wnorm, stream-serialized before us)
    int* hist = (int*)(ws + OFF_HIST);
    for (int e = idx; e < EE; e += 768 * 256) atomicAdd(&hist[dst[e]], 1);
}

// ---------------- CSR-by-dst construction ----------------
// two-level scan, stage 1: per-block exclusive prefix + block sums (196 blocks x 256)
__global__ __launch_bounds__(256) void scan_blocks_kernel(float* __restrict__ ws) {
    __shared__ int wsum[4];
    const int* hist = (const int*)(ws + OFF_HIST);
    int* starts = (int*)(ws + OFF_STARTS);
    int* bsum = (int*)(ws + OFF_SEV);              // scratch (sev written later by gemm_edge)
    int bid = blockIdx.x, t = threadIdx.x;
    int idx = bid * 256 + t;
    int lane = t & 63, w = t >> 6;
    int v = (idx < NN) ? hist[idx] : 0;
    int s = v;                                     // inclusive scan within wave
    #pragma unroll
    for (int o = 1; o < 64; o <<= 1) {
        int u = __shfl_up(s, o, 64);
        if (lane >= o) s += u;
    }
    if (lane == 63) wsum[w] = s;
    __syncthreads();
    int off = 0;
    for (int i = 0; i < w; ++i) off += wsum[i];
    int incl = s + off;
    if (idx < NN) starts[idx] = incl - v;          // exclusive prefix within block
    if (t == 255) bsum[bid] = incl;                // block total (inclusive)
}

// stage 2 (merged tops+add): each block derives its own prefix from raw block sums
__global__ __launch_bounds__(256) void scan_add_kernel(float* __restrict__ ws) {
    __shared__ int sb4[4];
    int* starts = (int*)(ws + OFF_STARTS);
    int* cursor = (int*)(ws + OFF_CURSOR);
    const int* bsum = (const int*)(ws + OFF_SEV);
    int bid = blockIdx.x, t = threadIdx.x;
    int lane = t & 63, w = t >> 6;
    // prefix = sum of bsum[j] for j < bid
    int v = (t < bid) ? bsum[t] : 0;               // bid <= SCAN_NB-1 < 256
    int s = v;
    #pragma unroll
    for (int o = 32; o > 0; o >>= 1) s += __shfl_down(s, o, 64);
    if (lane == 0) sb4[w] = s;
    __syncthreads();
    int prefix = sb4[0] + sb4[1] + sb4[2] + sb4[3];
    int idx = bid * 256 + t;
    if (idx < NN) {
        int sv = starts[idx] + prefix;
        starts[idx] = sv;
        cursor[idx] = sv;
    }
    if (idx == 0) starts[NN] = EE;
}

__global__ __launch_bounds__(256) void scatteridx_kernel(const int* __restrict__ src,
                                                         const int* __restrict__ dst,
                                                         float* __restrict__ ws) {
    int e = blockIdx.x * 256 + threadIdx.x;
    if (e >= EE) return;
    int d = dst[e];
    int pos = atomicAdd(&((int*)(ws + OFF_CURSOR))[d], 1);
    ((int2*)(ws + OFF_SSRCD))[pos] = make_int2(src[e], d);
}

// ---------------- node GEMM (MFMA fp16): converts feat, computes h/h2, vectorized hbf store ----
__global__ __launch_bounds__(256) void gemm_node_mfma(const float* __restrict__ feat,
                                                      const float* __restrict__ pool_b,
                                                      const float* __restrict__ pool2_b,
                                                      unsigned short* __restrict__ featbf,
                                                      unsigned short* __restrict__ hbf,
                                                      const unsigned short* __restrict__ wnodebf) {
    __shared__ unsigned short As[64 * 136];
    __shared__ unsigned short Hs[64 * 264];   // interleaved h/h2 repack (+8 pad breaks bank alias)
    int tid = threadIdx.x;
    int row0 = blockIdx.x * 64;
    #pragma unroll
    for (int it = 0; it < 8; ++it) {
        int idx = tid + it * 256;            // 64 rows x 32 float4-units
        int r = idx >> 5, u = idx & 31;
        int rr = min(row0 + r, NN - 1);
        float4 v = ((const float4*)feat)[rr * 32 + u];
        unsigned p0 = pk_f16(v.x, v.y);
        unsigned p1 = pk_f16(v.z, v.w);
        *(unsigned*)&As[r * 136 + u * 4]     = p0;
        *(unsigned*)&As[r * 136 + u * 4 + 2] = p1;
        *(uint2*)&featbf[rr * 128 + u * 4] = make_uint2(p0, p1);   // write fp16 feat table
    }
    __syncthreads();
    int lane = tid & 63, w = tid >> 6;
    int quad = lane >> 4, l15 = lane & 15;
    #pragma unroll 1
    for (int gy = 0; gy < 2; ++gy) {
        const unsigned short* B = wnodebf + (gy + 2) * 128 * 128;
        const float* bias = gy == 0 ? pool_b : pool2_b;
        f32x4 acc[8] = {};
        #pragma unroll 1
        for (int ks = 0; ks < 4; ++ks) {
            f16x8 a = *(const f16x8*)&As[(w * 16 + l15) * 136 + ks * 32 + quad * 8];
            #pragma unroll
            for (int t = 0; t < 8; ++t) {
                f16x8 b = *(const f16x8*)&B[(t * 16 + l15) * 128 + ks * 32 + quad * 8];
                acc[t] = __builtin_amdgcn_mfma_f32_16x16x32_f16(a, b, acc[t], 0, 0, 0);
            }
        }
        #pragma unroll
        for (int reg = 0; reg < 4; ++reg) {
            int lr = w * 16 + quad * 4 + reg;
            #pragma unroll
            for (int t = 0; t < 8; ++t) {
                int col = t * 16 + l15;
                // interleaved layout: col c of group gy -> (c>>1)*4 + (c&1) + gy*2
                Hs[lr * 264 + ((col >> 1) << 2) + (col & 1) + gy * 2] =
                    f2h(gelu_f(acc[t][reg] + bias[col]));
            }
        }
    }
    __syncthreads();
    #pragma unroll
    for (int it = 0; it < 8; ++it) {          // 64 rows x 32 8-ushort chunks, 16B stores
        int idx = tid + it * 256;
        int r = idx >> 5, u = idx & 31;
        int row = row0 + r;
        if (row < NN)
            *(uint4*)&hbf[row * 256 + u * 8] = *(const uint4*)&Hs[r * 264 + u * 8];
    }
}

// ---------------- edge GEMM: fused K=384 [fs*fd | fs | fd] @ B (fp16), B LDS-staged dbuf
// (48 KB, 3 blocks/CU — register-bound occupancy, R8-proven), T14 split, A prefetch d2 ----
__global__ __launch_bounds__(256, 3) void gemm_edge(const unsigned short* __restrict__ featbf,
                                                    const unsigned short* __restrict__ wedgebf,
                                                    float* __restrict__ ws) {
    __shared__ unsigned short Bs[2][24 * 512];   // 2 x 24 KB (24 fragments x 64 lanes x 8 fp16)
    int tid = threadIdx.x;
    int lane = tid & 63, w = tid >> 6;
    int quad = lane >> 4, l15 = lane & 15;
    int e0 = blockIdx.x * 128;
    const int2* ssrcd = (const int2*)(ws + OFF_SSRCD);
    int base = e0 + w * 32 + l15;                // wave handles edges [e0+w*32, +32)
    int2 i0 = ssrcd[base];
    int2 i1 = ssrcd[base + 16];
    const unsigned short* p0s = &featbf[i0.x * 128];
    const unsigned short* p0d = &featbf[i0.y * 128];
    const unsigned short* p1s = &featbf[i1.x * 128];
    const unsigned short* p1d = &featbf[i1.y * 128];
    int ko = quad * 8;

    // ---- prologue: A chunks kb0,kb1; B stage kb0 ----
    uint4 ca[2][4];                              // A double-buffer [kb&1][stream]
    ca[0][0] = *(const uint4*)&p0s[ko];
    ca[0][1] = *(const uint4*)&p0d[ko];
    ca[0][2] = *(const uint4*)&p1s[ko];
    ca[0][3] = *(const uint4*)&p1d[ko];
    ca[1][0] = *(const uint4*)&p0s[ko + 32];
    ca[1][1] = *(const uint4*)&p0d[ko + 32];
    ca[1][2] = *(const uint4*)&p1s[ko + 32];
    ca[1][3] = *(const uint4*)&p1d[ko + 32];
    uint4 sb[6];                                 // B staging regs: wave w owns frags ts = w*6..w*6+5
    #pragma unroll
    for (int i = 0; i < 6; ++i) {
        int ts = w * 6 + i;
        sb[i] = *(const uint4*)&wedgebf[(ts * 4 + 0) * 512 + lane * 8];
    }
    #pragma unroll
    for (int i = 0; i < 6; ++i) {
        int ts = w * 6 + i;
        *(uint4*)&Bs[0][ts * 512 + lane * 8] = sb[i];
    }
    __syncthreads();

    f32x4 acc0[8] = {}, acc1[8] = {};
    #pragma unroll
    for (int kb = 0; kb < 4; ++kb) {
        // consume current A chunk into fp16 fragments (before overwrite by prefetch)
        uint4 c0s = ca[kb & 1][0], c0d = ca[kb & 1][1];
        uint4 c1s = ca[kb & 1][2], c1d = ca[kb & 1][3];
        uint4 m0, m1;                            // elementwise fs*fd via v_pk_mul_f16
        m0.x = mulpack_h(c0s.x, c0d.x); m0.y = mulpack_h(c0s.y, c0d.y);
        m0.z = mulpack_h(c0s.z, c0d.z); m0.w = mulpack_h(c0s.w, c0d.w);
        m1.x = mulpack_h(c1s.x, c1d.x); m1.y = mulpack_h(c1s.y, c1d.y);
        m1.z = mulpack_h(c1s.z, c1d.z); m1.w = mulpack_h(c1s.w, c1d.w);
        f16x8 am0 = *(const f16x8*)&m0,  am1 = *(const f16x8*)&m1;
        f16x8 as0 = *(const f16x8*)&c0s, ad0 = *(const f16x8*)&c0d;
        f16x8 as1 = *(const f16x8*)&c1s, ad1 = *(const f16x8*)&c1d;
        // issue A prefetch for kb+2 into the freed slot
        if (kb < 2) {
            int k2 = ko + (kb + 2) * 32;
            ca[kb & 1][0] = *(const uint4*)&p0s[k2];
            ca[kb & 1][1] = *(const uint4*)&p0d[k2];
            ca[kb & 1][2] = *(const uint4*)&p1s[k2];
            ca[kb & 1][3] = *(const uint4*)&p1d[k2];
        }
        // issue B global loads for kb+1 (write to LDS after MFMA phase — T14 split)
        if (kb < 3) {
            #pragma unroll
            for (int i = 0; i < 6; ++i) {
                int ts = w * 6 + i;
                sb[i] = *(const uint4*)&wedgebf[(ts * 4 + kb + 1) * 512 + lane * 8];
            }
        }
        // MFMA phase: B from LDS (ds_read_b128, conflict-free)
        const unsigned short* bb = &Bs[kb & 1][lane * 8];
        #pragma unroll
        for (int t = 0; t < 8; ++t) {
            f16x8 bm = *(const f16x8*)&bb[(t * 3 + 0) * 512];
            f16x8 b1 = *(const f16x8*)&bb[(t * 3 + 1) * 512];
            f16x8 b2 = *(const f16x8*)&bb[(t * 3 + 2) * 512];
            acc0[t] = __builtin_amdgcn_mfma_f32_16x16x32_f16(am0, bm, acc0[t], 0, 0, 0);
            acc1[t] = __builtin_amdgcn_mfma_f32_16x16x32_f16(am1, bm, acc1[t], 0, 0, 0);
            acc0[t] = __builtin_amdgcn_mfma_f32_16x16x32_f16(as0, b1, acc0[t], 0, 0, 0);
            acc1[t] = __builtin_amdgcn_mfma_f32_16x16x32_f16(as1, b1, acc1[t], 0, 0, 0);
            acc0[t] = __builtin_amdgcn_mfma_f32_16x16x32_f16(ad0, b2, acc0[t], 0, 0, 0);
            acc1[t] = __builtin_amdgcn_mfma_f32_16x16x32_f16(ad1, b2, acc1[t], 0, 0, 0);
        }
        // write-late: staged B -> LDS buf for kb+1, then barrier
        if (kb < 3) {
            #pragma unroll
            for (int i = 0; i < 6; ++i) {
                int ts = w * 6 + i;
                *(uint4*)&Bs[(kb + 1) & 1][ts * 512 + lane * 8] = sb[i];
            }
            __syncthreads();
        }
    }

    // epilogue: e = leaky(sum_col gelu(acc + be) * waout + b_aout)
    const float* waout = ws + OFF_WAOUT;
    const float* be = ws + OFF_BE;
    float b_aout = ws[OFF_BAOUT];
    float* e_out = ws + OFF_SEV;
    float wv[8], bv[8];
    #pragma unroll
    for (int t = 0; t < 8; ++t) { wv[t] = waout[t * 16 + l15]; bv[t] = be[t * 16 + l15]; }
    #pragma unroll
    for (int g = 0; g < 2; ++g) {
        #pragma unroll
        for (int reg = 0; reg < 4; ++reg) {
            int r = w * 32 + g * 16 + quad * 4 + reg;
            float partial = 0.0f;
            #pragma unroll
            for (int t = 0; t < 8; ++t) {
                float v = (g ? acc1[t][reg] : acc0[t][reg]) + bv[t];
                partial += gelu_f(v) * wv[t];
            }
            partial += __shfl_xor(partial, 1, 16);
            partial += __shfl_xor(partial, 2, 16);
            partial += __shfl_xor(partial, 4, 16);
            partial += __shfl_xor(partial, 8, 16);
            if (l15 == 0) e_out[e0 + r] = leaky_f(partial + b_aout);
        }
    }
}

// ---------------- fused segreduce + final GEMM (K=384) + 2 MLP layers -> out f32 -------------
// Each wave computes neigh/neigh2 for its own 16 rows directly into the As LDS tile (no
// neighbf round-trip), then the block proceeds with the K=384 GEMM and in-register MLP.
__global__ __launch_bounds__(256) void gemm_final_mlp(const unsigned short* __restrict__ featbf,
                                                      const unsigned short* __restrict__ wfinbf,
                                                      const unsigned short* __restrict__ wmlpbf,
                                                      const float* __restrict__ mlp_b,
                                                      float* __restrict__ out,
                                                      const float* __restrict__ ws) {
    __shared__ unsigned short As[64 * 392];   // [64 rows][neigh 0..127 | neigh2 128..255 | feat 256..383]
    __shared__ float bfin_s[128];
    int tid = threadIdx.x;
    int row0 = blockIdx.x * 64;
    if (tid < 128) bfin_s[tid] = ws[OFF_BFIN + tid];
    // stage feat rows into As cols 256..383 (global loads overlap the gather loop below)
    #pragma unroll
    for (int it = 0; it < 4; ++it) {
        int idx = tid + it * 256;
        int r = idx >> 4, u = idx & 15;
        int rr = min(row0 + r, NN - 1);
        *(uint4*)&As[r * 392 + 256 + u * 8] = *(const uint4*)&featbf[rr * 128 + u * 8];
    }
    int lane = tid & 63, w = tid >> 6;
    // segreduce phase: wave w computes rows w*16 .. w*16+15
    {
        const int* starts = (const int*)(ws + OFF_STARTS);
        const int2* ssrcd = (const int2*)(ws + OFF_SSRCD);
        const float* sev = ws + OFF_SEV;
        const unsigned short* hbf = (const unsigned short*)(ws + OFF_HBF);
        for (int j = 0; j < 16; ++j) {
            int r = w * 16 + j;
            int n = min(row0 + r, NN - 1);
            int s0 = starts[n], s1 = starts[n + 1];
            float2 mx = make_float2(-INFINITY, -INFINITY);
            float2 sm = make_float2(0.f, 0.f);
            int i = s0;
            for (; i + 4 <= s1; i += 4) {
                int sA = ssrcd[i].x, sB = ssrcd[i + 1].x, sC = ssrcd[i + 2].x, sD = ssrcd[i + 3].x;
                float eA = sev[i], eB = sev[i + 1], eC = sev[i + 2], eD = sev[i + 3];
                uint2 vA = *(const uint2*)&hbf[sA * 256 + lane * 4];   // (h pair, h2 pair)
                uint2 vB = *(const uint2*)&hbf[sB * 256 + lane * 4];
                uint2 vC = *(const uint2*)&hbf[sC * 256 + lane * 4];
                uint2 vD = *(const uint2*)&hbf[sD * 256 + lane * 4];
                float2 hA = up2(vA.x), gA = up2(vA.y);
                float2 hB = up2(vB.x), gB = up2(vB.y);
                float2 hC = up2(vC.x), gC = up2(vC.y);
                float2 hD = up2(vD.x), gD = up2(vD.y);
                mx.x = fmaxf(mx.x, eA * hA.x); mx.y = fmaxf(mx.y, eA * hA.y);
                sm.x += eA * gA.x;             sm.y += eA * gA.y;
                mx.x = fmaxf(mx.x, eB * hB.x); mx.y = fmaxf(mx.y, eB * hB.y);
                sm.x += eB * gB.x;             sm.y += eB * gB.y;
                mx.x = fmaxf(mx.x, eC * hC.x); mx.y = fmaxf(mx.y, eC * hC.y);
                sm.x += eC * gC.x;             sm.y += eC * gC.y;
                mx.x = fmaxf(mx.x, eD * hD.x); mx.y = fmaxf(mx.y, eD * hD.y);
                sm.x += eD * gD.x;             sm.y += eD * gD.y;
            }
            for (; i < s1; ++i) {
                int s = ssrcd[i].x;
                float ev = sev[i];
                uint2 v = *(const uint2*)&hbf[s * 256 + lane * 4];
                float2 h = up2(v.x), g = up2(v.y);
                mx.x = fmaxf(mx.x, ev * h.x); mx.y = fmaxf(mx.y, ev * h.y);
                sm.x += ev * g.x;             sm.y += ev * g.y;
            }
            int cnt = s1 - s0;
            if (cnt == 0) { mx.x = 0.f; mx.y = 0.f; }
            float ic = 1.0f / (float)max(cnt, 1);
            *(unsigned*)&As[r * 392 + lane * 2]       = pk_f16(mx.x, mx.y);
            *(unsigned*)&As[r * 392 + 128 + lane * 2] = pk_f16(sm.x * ic, sm.y * ic);
        }
    }
    __syncthreads();
    int quad = lane >> 4, l15 = lane & 15;
    f32x4 rst[8] = {};
    #pragma unroll 1
    for (int ks = 0; ks < 12; ++ks) {
        f16x8 a = *(const f16x8*)&As[(w * 16 + l15) * 392 + ks * 32 + quad * 8];
        #pragma unroll
        for (int t = 0; t < 8; ++t) {
            f16x8 b = *(const f16x8*)&wfinbf[(t * 16 + l15) * 384 + ks * 32 + quad * 8];
            rst[t] = __builtin_amdgcn_mfma_f32_16x16x32_f16(a, b, rst[t], 0, 0, 0);
        }
    }
    #pragma unroll
    for (int t = 0; t < 8; ++t) {
        float bf = bfin_s[t * 16 + l15];
        #pragma unroll
        for (int reg = 0; reg < 4; ++reg) rst[t][reg] += bf;
    }
    // two residual MLP layers, all in-block (no global round trip)
    #pragma unroll 1
    for (int layer = 0; layer < 2; ++layer) {
        __syncthreads();                       // prior As reads complete before overwrite
        #pragma unroll
        for (int t = 0; t < 8; ++t) {
            #pragma unroll
            for (int reg = 0; reg < 4; ++reg) {
                int row = w * 16 + quad * 4 + reg;
                As[row * 136 + t * 16 + l15] = f2h(gelu_f(rst[t][reg]));
            }
        }
        __syncthreads();
        const unsigned short* wB = wmlpbf + layer * 16384;
        f32x4 acc[8] = {};
        #pragma unroll 1
        for (int ks = 0; ks < 4; ++ks) {
            f16x8 a = *(const f16x8*)&As[(w * 16 + l15) * 136 + ks * 32 + quad * 8];
            #pragma unroll
            for (int t = 0; t < 8; ++t) {
                f16x8 b = *(const f16x8*)&wB[(t * 16 + l15) * 128 + ks * 32 + quad * 8];
                acc[t] = __builtin_amdgcn_mfma_f32_16x16x32_f16(a, b, acc[t], 0, 0, 0);
            }
        }
        #pragma unroll
        for (int t = 0; t < 8; ++t) {
            float bias = mlp_b[layer * 128 + t * 16 + l15];
            #pragma unroll
            for (int reg = 0; reg < 4; ++reg) rst[t][reg] += acc[t][reg] + bias;
        }
    }
    #pragma unroll
    for (int reg = 0; reg < 4; ++reg) {
        int row = row0 + w * 16 + quad * 4 + reg;
        if (row >= NN) continue;
        #pragma unroll
        for (int t = 0; t < 8; ++t) {
            out[row * 128 + t * 16 + l15] = rst[t][reg];
        }
    }
}

// ---------------- host launch ----------------
extern "C" void kernel_launch(void* const* d_in, const int* in_sizes, int n_in,
                              void* d_out, int out_size, void* d_ws, size_t ws_size,
                              hipStream_t stream) {
    const float* feat = (const float*)d_in[0];
    WnormArgs wa;
    wa.asrc_v = (const float*)d_in[1];  wa.asrc_g = (const float*)d_in[2];  wa.asrc_b = (const float*)d_in[3];
    wa.adst_v = (const float*)d_in[4];  wa.adst_g = (const float*)d_in[5];  wa.adst_b = (const float*)d_in[6];
    wa.asub_v = (const float*)d_in[7];  wa.asub_g = (const float*)d_in[8];  wa.asub_b = (const float*)d_in[9];
    wa.amul_v = (const float*)d_in[10]; wa.amul_g = (const float*)d_in[11]; wa.amul_b = (const float*)d_in[12];
    wa.aout_v = (const float*)d_in[13]; wa.aout_g = (const float*)d_in[14]; wa.aout_b = (const float*)d_in[15];
    wa.pool_v = (const float*)d_in[16]; wa.pool_g = (const float*)d_in[17]; wa.pool_b = (const float*)d_in[18];
    wa.pool2_v= (const float*)d_in[19]; wa.pool2_g= (const float*)d_in[20]; wa.pool2_b= (const float*)d_in[21];
    wa.self_v = (const float*)d_in[22]; wa.self_g = (const float*)d_in[23]; wa.self_b = (const float*)d_in[24];
    wa.neigh_v= (const float*)d_in[25]; wa.neigh_g= (const float*)d_in[26]; wa.neigh_b= (const float*)d_in[27];
    wa.neigh2_v=(const float*)d_in[28]; wa.neigh2_g=(const float*)d_in[29]; wa.neigh2_b=(const float*)d_in[30];
    wa.mlp_v  = (const float*)d_in[31]; wa.mlp_g  = (const float*)d_in[32]; wa.mlp_b  = (const float*)d_in[33];
    const int* src = (const int*)d_in[34];
    const int* dst = (const int*)d_in[35];
    float* out = (float*)d_out;
    float* ws = (float*)d_ws;
    wa.ws = ws;
    unsigned short* featbf  = (unsigned short*)(ws + OFF_FEATBF);
    unsigned short* hbf     = (unsigned short*)(ws + OFF_HBF);
    unsigned short* wnodebf = (unsigned short*)(ws + OFF_WNODEBF);
    unsigned short* wfinbf  = (unsigned short*)(ws + OFF_WFINBF);
    unsigned short* wmlpbf  = (unsigned short*)(ws + OFF_WMLPBF);
    unsigned short* wedgebf = (unsigned short*)(ws + OFF_WEDGEBF);

    // 1) normalized weights + fused bias vectors (+ hist zero)
    wnorm_kernel<<<dim3(1281), dim3(128), 0, stream>>>(wa);
    // 2) weight tables -> fp16 (+ fused dst histogram)
    convert_weights_kernel<<<dim3(768), dim3(256), 0, stream>>>(dst, ws);
    // 3) CSR-by-dst (two-level parallel scan; tops merged into add)
    scan_blocks_kernel<<<dim3(SCAN_NB), dim3(256), 0, stream>>>(ws);
    scan_add_kernel<<<dim3(SCAN_NB), dim3(256), 0, stream>>>(ws);
    scatteridx_kernel<<<dim3((EE + 255) / 256), dim3(256), 0, stream>>>(src, dst, ws);
    // 4) node GEMM (MFMA fp16): converts feat->fp16, computes h/h2, vectorized hbf store
    gemm_node_mfma<<<dim3(782), dim3(256), 0, stream>>>(feat, wa.pool_b, wa.pool2_b, featbf, hbf, wnodebf);
    // 5) edge GEMM (fused K=384, dbuf LDS B, 3 waves/SIMD — R8-proven) -> sev
    gemm_edge<<<dim3(EE / 128), dim3(256), 0, stream>>>(featbf, wedgebf, ws);
    // 6) fused segreduce + final GEMM + 2 MLP layers -> out (no neighbf round-trip)
    gemm_final_mlp<<<dim3(782), dim3(256), 0, stream>>>(featbf, wfinbf, wmlpbf, wa.mlp_b, out, ws);
}

// Round 13
// 507.813 us; speedup vs baseline: 1.1013x; 1.1013x over previous
//
#include <hip/hip_runtime.h>
#include <hip/hip_bf16.h>
#include <math.h>

// ---------------- problem constants ----------------
constexpr int NN = 50000;   // nodes
constexpr int EE = 800000;  // edges

// ---------------- workspace layout (float offsets) ----------------
// f32 weights (written by wnorm)
constexpr int OFF_WT_NODE  = 0;        // [128][512] k-major: col groups 0:asrc+asub 1:adst-asub 2:pool 3:pool2
constexpr int OFF_WT_AMUL  = 65536;    // [128][128] k-major
constexpr int OFF_WT_FINAL = 81920;    // [384][128] k-major; k: 0-127 neigh, 128-255 neigh2, 256-383 self
constexpr int OFF_WT_MLP   = 131072;   // 2 x [128][128] k-major
constexpr int OFF_WAOUT    = 163840;   // [128]
constexpr int OFF_BE       = 163968;   // [128]
constexpr int OFF_BFIN     = 164096;   // [128]
constexpr int OFF_BAOUT    = 164224;   // [1] (pad 16)
// fp16 transposed weight tables ([o][k])
constexpr int OFF_WNODEBF  = 164240;               // 512*128 ushort = 32768 fl
constexpr int OFF_WFINBF   = OFF_WNODEBF + 32768;  // 128*384 ushort = 24576 fl
constexpr int OFF_WMLPBF   = OFF_WFINBF + 24576;   // 2*128*128 ushort = 16384 fl
constexpr int OFF_WAMULBF  = OFF_WMLPBF + 16384;   // (unused, layout keeper)
// big arrays
constexpr int OFF_FEATBF   = OFF_WAMULBF + 8192;   // [N][128] fp16
constexpr int OFF_SBF      = OFF_FEATBF + NN*64;   // region reused: edge fused weight table
constexpr int OFF_WEDGEBF  = OFF_SBF;              // packed fragments: [(t*3+slice)*4+kb][lane 64][8] fp16
constexpr int OFF_HBF      = OFF_SBF + NN*128;     // [N][256] fp16 INTERLEAVED: pos (c>>1)*4+(c&1)+grp*2
constexpr int OFF_SEV      = OFF_HBF + NN*128;     // [E] f32, dst-sorted e (scratch for scan blocksums pre-edge)
constexpr int OFF_NEIGHBF  = OFF_SEV + EE;         // [N][256] fp16 (neigh | neigh2)
constexpr int OFF_STARTS   = OFF_NEIGHBF + NN*128; // [N+1] int (+pad)
constexpr int OFF_HIST     = OFF_STARTS + NN + 8;  // [N] int
constexpr int OFF_CURSOR   = OFF_HIST + NN;        // [N] int
constexpr int OFF_SSRCD    = OFF_CURSOR + NN;      // [E] int2 (src,dst sorted by dst)

constexpr int SCAN_NB = (NN + 255) / 256;          // 196 scan blocks

typedef __attribute__((ext_vector_type(8))) _Float16 f16x8;
typedef __attribute__((ext_vector_type(2))) _Float16 f16x2;
typedef __attribute__((ext_vector_type(2))) __fp16 fp16x2r;   // builtin cvt_pkrtz return type
typedef __attribute__((ext_vector_type(4))) float f32x4;

// ---------------- device helpers ----------------
// fast GELU (tanh form via sigmoid), log2e folded into polynomial, rcp instead of div.
__device__ __forceinline__ float gelu_f(float x) {
    float x2 = x * x;
    float w = x * fmaf(-0.1029448f, x2, -2.3022082f);
    return x * __builtin_amdgcn_rcpf(1.0f + __builtin_amdgcn_exp2f(w));
}
__device__ __forceinline__ float leaky_f(float x) {
    return x > 0.0f ? x : 0.2f * x;
}
// packed 2x f32 -> fp16x2 in one v_cvt_pkrtz_f16_f32
__device__ __forceinline__ unsigned pk_f16(float lo, float hi) {
    fp16x2r p = __builtin_amdgcn_cvt_pkrtz(lo, hi);
    return *reinterpret_cast<unsigned*>(&p);
}
__device__ __forceinline__ unsigned short f2h(float x) {
    fp16x2r p = __builtin_amdgcn_cvt_pkrtz(x, 0.0f);
    return *reinterpret_cast<unsigned short*>(&p);
}
// packed fp16 multiply: one v_pk_mul_f16
__device__ __forceinline__ unsigned mulpack_h(unsigned a, unsigned b) {
    f16x2 x = *reinterpret_cast<f16x2*>(&a);
    f16x2 y = *reinterpret_cast<f16x2*>(&b);
    f16x2 r = x * y;
    return *reinterpret_cast<unsigned*>(&r);
}
__device__ __forceinline__ float2 up2(unsigned u) {
    f16x2 p = *reinterpret_cast<f16x2*>(&u);
    return make_float2((float)p.x, (float)p.y);
}
__device__ __forceinline__ float block_sum128(float v, float* sbuf) {
    #pragma unroll
    for (int o = 32; o > 0; o >>= 1) v += __shfl_down(v, o, 64);
    int lane = threadIdx.x & 63, w = threadIdx.x >> 6;
    if (lane == 0) sbuf[w] = v;
    __syncthreads();
    float r = sbuf[0] + sbuf[1];
    __syncthreads();
    return r;
}

// ---------------- weight normalization (+ hist zero piggyback) ----------------
struct WnormArgs {
    const float *asrc_v, *asrc_g, *asrc_b;
    const float *adst_v, *adst_g, *adst_b;
    const float *asub_v, *asub_g, *asub_b;
    const float *amul_v, *amul_g, *amul_b;
    const float *aout_v, *aout_g, *aout_b;
    const float *pool_v, *pool_g, *pool_b;
    const float *pool2_v, *pool2_g, *pool2_b;
    const float *self_v, *self_g, *self_b;
    const float *neigh_v, *neigh_g, *neigh_b;
    const float *neigh2_v, *neigh2_g, *neigh2_b;
    const float *mlp_v, *mlp_g, *mlp_b;
    float* ws;
};

__global__ __launch_bounds__(128) void wnorm_kernel(WnormArgs a) {
    __shared__ float sbuf[2];
    int bid = blockIdx.x, i = threadIdx.x;
    float* ws = a.ws;
    int gid = bid * 128 + i;
    if (gid < NN) ((int*)(ws + OFF_HIST))[gid] = 0;   // fused hist_zero
    if (bid < 1280) {
        int o = bid & 127, grp = bid >> 7;
        const float *v1 = nullptr, *g1 = nullptr, *v2 = nullptr, *g2 = nullptr;
        float sgn2 = 1.0f; float* dst = nullptr; int stride = 0;
        switch (grp) {
            case 0: v1=a.asrc_v; g1=a.asrc_g; v2=a.asub_v; g2=a.asub_g; sgn2= 1.f; dst=ws+OFF_WT_NODE+o;        stride=512; break;
            case 1: v1=a.adst_v; g1=a.adst_g; v2=a.asub_v; g2=a.asub_g; sgn2=-1.f; dst=ws+OFF_WT_NODE+128+o;    stride=512; break;
            case 2: v1=a.pool_v;  g1=a.pool_g;  dst=ws+OFF_WT_NODE+256+o;          stride=512; break;
            case 3: v1=a.pool2_v; g1=a.pool2_g; dst=ws+OFF_WT_NODE+384+o;          stride=512; break;
            case 4: v1=a.amul_v;  g1=a.amul_g;  dst=ws+OFF_WT_AMUL+o;              stride=128; break;
            case 5: v1=a.neigh_v; g1=a.neigh_g; dst=ws+OFF_WT_FINAL+o;             stride=128; break;
            case 6: v1=a.neigh2_v;g1=a.neigh2_g;dst=ws+OFF_WT_FINAL+128*128+o;     stride=128; break;
            case 7: v1=a.self_v;  g1=a.self_g;  dst=ws+OFF_WT_FINAL+256*128+o;     stride=128; break;
            case 8: v1=a.mlp_v;        g1=a.mlp_g;     dst=ws+OFF_WT_MLP+o;        stride=128; break;
            case 9: v1=a.mlp_v+16384;  g1=a.mlp_g+128; dst=ws+OFF_WT_MLP+16384+o;  stride=128; break;
        }
        float x1 = v1[o*128 + i];
        float n1 = sqrtf(block_sum128(x1*x1, sbuf));
        float w = g1[o] * x1 / n1;
        if (v2) {
            float x2 = v2[o*128 + i];
            float n2 = sqrtf(block_sum128(x2*x2, sbuf));
            w += sgn2 * g2[o] * x2 / n2;
        }
        dst[i * stride] = w;
    } else {
        float v = a.aout_v[i];
        float n = sqrtf(block_sum128(v*v, sbuf));
        ws[OFF_WAOUT + i] = a.aout_g[0] * v / n;
        ws[OFF_BE + i]    = a.asrc_b[i] + a.adst_b[i] + a.asub_b[i] + a.amul_b[i];
        ws[OFF_BFIN + i]  = a.self_b[i] + a.neigh_b[i] + a.neigh2_b[i];
        if (i == 0) ws[OFF_BAOUT] = a.aout_b[0];
    }
}

// ---------------- weight tables -> fp16 (+ fused dst histogram); 768 blocks x 256 ----------------
__global__ __launch_bounds__(256) void convert_weights_kernel(const int* __restrict__ dst,
                                                              float* __restrict__ ws) {
    int idx = blockIdx.x * 256 + threadIdx.x;
    unsigned short* wnodebf = (unsigned short*)(ws + OFF_WNODEBF);
    unsigned short* wfinbf  = (unsigned short*)(ws + OFF_WFINBF);
    unsigned short* wmlpbf  = (unsigned short*)(ws + OFF_WMLPBF);
    unsigned short* wedgebf = (unsigned short*)(ws + OFF_WEDGEBF);
    if (idx < 65536) {                 // node: [k 128][n 512] -> [n][k]
        int k = idx >> 9, n = idx & 511;
        wnodebf[n * 128 + k] = f2h(ws[OFF_WT_NODE + k * 512 + n]);
    } else if (idx < 114688) {         // final: [k 384][o 128] -> [o][k]
        int i = idx - 65536, k = i >> 7, o = i & 127;
        wfinbf[o * 384 + k] = f2h(ws[OFF_WT_FINAL + k * 128 + o]);
    } else if (idx < 147456) {         // mlp: 2 x [k 128][o 128] -> [o][k]
        int i = idx - 114688, l = i >> 14, j = i & 16383, k = j >> 7, o = j & 127;
        wmlpbf[l * 16384 + o * 128 + k] = f2h(ws[OFF_WT_MLP + l * 16384 + k * 128 + o]);
    } else {
        // packed fused edge table: fragment id f = (t*3+slice)*4+kb; layout [f][lane 64][elem 8]
        int i = idx - 147456;              // [0, 49152)
        int elem = i & 7, f = i >> 3;
        int lane = f & 63, kb = (f >> 6) & 3, ts = f >> 8;   // ts in [0,24)
        int t = ts / 3, slice = ts - t * 3;
        int o = t * 16 + (lane & 15);
        int kk = kb * 32 + (lane >> 4) * 8 + elem;
        float v = (slice == 0) ? ws[OFF_WT_AMUL + kk * 128 + o]
                : (slice == 1) ? ws[OFF_WT_NODE + kk * 512 + o]
                               : ws[OFF_WT_NODE + kk * 512 + 128 + o];
        wedgebf[i] = f2h(v);
    }
    // fused dst histogram (hist zeroed by wnorm, stream-serialized before us)
    int* hist = (int*)(ws + OFF_HIST);
    for (int e = idx; e < EE; e += 768 * 256) atomicAdd(&hist[dst[e]], 1);
}

// ---------------- CSR-by-dst construction ----------------
// two-level scan, stage 1: per-block exclusive prefix + block sums (196 blocks x 256)
__global__ __launch_bounds__(256) void scan_blocks_kernel(float* __restrict__ ws) {
    __shared__ int wsum[4];
    const int* hist = (const int*)(ws + OFF_HIST);
    int* starts = (int*)(ws + OFF_STARTS);
    int* bsum = (int*)(ws + OFF_SEV);              // scratch (sev written later by gemm_edge)
    int bid = blockIdx.x, t = threadIdx.x;
    int idx = bid * 256 + t;
    int lane = t & 63, w = t >> 6;
    int v = (idx < NN) ? hist[idx] : 0;
    int s = v;                                     // inclusive scan within wave
    #pragma unroll
    for (int o = 1; o < 64; o <<= 1) {
        int u = __shfl_up(s, o, 64);
        if (lane >= o) s += u;
    }
    if (lane == 63) wsum[w] = s;
    __syncthreads();
    int off = 0;
    for (int i = 0; i < w; ++i) off += wsum[i];
    int incl = s + off;
    if (idx < NN) starts[idx] = incl - v;          // exclusive prefix within block
    if (t == 255) bsum[bid] = incl;                // block total (inclusive)
}

// stage 2 (merged tops+add): each block derives its own prefix from raw block sums
__global__ __launch_bounds__(256) void scan_add_kernel(float* __restrict__ ws) {
    __shared__ int sb4[4];
    int* starts = (int*)(ws + OFF_STARTS);
    int* cursor = (int*)(ws + OFF_CURSOR);
    const int* bsum = (const int*)(ws + OFF_SEV);
    int bid = blockIdx.x, t = threadIdx.x;
    int lane = t & 63, w = t >> 6;
    // prefix = sum of bsum[j] for j < bid
    int v = (t < bid) ? bsum[t] : 0;               // bid <= SCAN_NB-1 < 256
    int s = v;
    #pragma unroll
    for (int o = 32; o > 0; o >>= 1) s += __shfl_down(s, o, 64);
    if (lane == 0) sb4[w] = s;
    __syncthreads();
    int prefix = sb4[0] + sb4[1] + sb4[2] + sb4[3];
    int idx = bid * 256 + t;
    if (idx < NN) {
        int sv = starts[idx] + prefix;
        starts[idx] = sv;
        cursor[idx] = sv;
    }
    if (idx == 0) starts[NN] = EE;
}

__global__ __launch_bounds__(256) void scatteridx_kernel(const int* __restrict__ src,
                                                         const int* __restrict__ dst,
                                                         float* __restrict__ ws) {
    int e = blockIdx.x * 256 + threadIdx.x;
    if (e >= EE) return;
    int d = dst[e];
    int pos = atomicAdd(&((int*)(ws + OFF_CURSOR))[d], 1);
    ((int2*)(ws + OFF_SSRCD))[pos] = make_int2(src[e], d);
}

// ---------------- segmented reduction -> neighbf fp16 [N][256], 4-wide, 8B fused h/h2 loads ----
__global__ __launch_bounds__(256) void segreduce_kernel(float* __restrict__ ws) {
    int n = blockIdx.x * 4 + (threadIdx.x >> 6);
    int lane = threadIdx.x & 63;
    const int* starts = (const int*)(ws + OFF_STARTS);
    const int2* ssrcd = (const int2*)(ws + OFF_SSRCD);
    const float* sev = ws + OFF_SEV;
    const unsigned short* hbf = (const unsigned short*)(ws + OFF_HBF);
    unsigned short* neighbf = (unsigned short*)(ws + OFF_NEIGHBF);
    int s0 = starts[n], s1 = starts[n + 1];
    float2 mx = make_float2(-INFINITY, -INFINITY);
    float2 sm = make_float2(0.f, 0.f);
    int i = s0;
    for (; i + 4 <= s1; i += 4) {
        int sA = ssrcd[i].x, sB = ssrcd[i + 1].x, sC = ssrcd[i + 2].x, sD = ssrcd[i + 3].x;
        float eA = sev[i], eB = sev[i + 1], eC = sev[i + 2], eD = sev[i + 3];
        uint2 vA = *(const uint2*)&hbf[sA * 256 + lane * 4];   // (h pair, h2 pair)
        uint2 vB = *(const uint2*)&hbf[sB * 256 + lane * 4];
        uint2 vC = *(const uint2*)&hbf[sC * 256 + lane * 4];
        uint2 vD = *(const uint2*)&hbf[sD * 256 + lane * 4];
        float2 hA = up2(vA.x), gA = up2(vA.y);
        float2 hB = up2(vB.x), gB = up2(vB.y);
        float2 hC = up2(vC.x), gC = up2(vC.y);
        float2 hD = up2(vD.x), gD = up2(vD.y);
        mx.x = fmaxf(mx.x, eA * hA.x); mx.y = fmaxf(mx.y, eA * hA.y);
        sm.x += eA * gA.x;             sm.y += eA * gA.y;
        mx.x = fmaxf(mx.x, eB * hB.x); mx.y = fmaxf(mx.y, eB * hB.y);
        sm.x += eB * gB.x;             sm.y += eB * gB.y;
        mx.x = fmaxf(mx.x, eC * hC.x); mx.y = fmaxf(mx.y, eC * hC.y);
        sm.x += eC * gC.x;             sm.y += eC * gC.y;
        mx.x = fmaxf(mx.x, eD * hD.x); mx.y = fmaxf(mx.y, eD * hD.y);
        sm.x += eD * gD.x;             sm.y += eD * gD.y;
    }
    for (; i < s1; ++i) {
        int s = ssrcd[i].x;
        float ev = sev[i];
        uint2 v = *(const uint2*)&hbf[s * 256 + lane * 4];
        float2 h = up2(v.x), g = up2(v.y);
        mx.x = fmaxf(mx.x, ev * h.x); mx.y = fmaxf(mx.y, ev * h.y);
        sm.x += ev * g.x;             sm.y += ev * g.y;
    }
    int cnt = s1 - s0;
    if (cnt == 0) { mx.x = 0.f; mx.y = 0.f; }
    float ic = 1.0f / (float)max(cnt, 1);
    *(unsigned*)&neighbf[n * 256 + lane * 2] = pk_f16(mx.x, mx.y);
    *(unsigned*)&neighbf[n * 256 + 128 + lane * 2] = pk_f16(sm.x * ic, sm.y * ic);
}

// ---------------- node GEMM (MFMA fp16): converts feat, computes h/h2, vectorized hbf store ----
__global__ __launch_bounds__(256) void gemm_node_mfma(const float* __restrict__ feat,
                                                      const float* __restrict__ pool_b,
                                                      const float* __restrict__ pool2_b,
                                                      unsigned short* __restrict__ featbf,
                                                      unsigned short* __restrict__ hbf,
                                                      const unsigned short* __restrict__ wnodebf) {
    __shared__ unsigned short As[64 * 136];
    __shared__ unsigned short Hs[64 * 264];   // interleaved h/h2 repack (+8 pad breaks bank alias)
    int tid = threadIdx.x;
    int row0 = blockIdx.x * 64;
    #pragma unroll
    for (int it = 0; it < 8; ++it) {
        int idx = tid + it * 256;            // 64 rows x 32 float4-units
        int r = idx >> 5, u = idx & 31;
        int rr = min(row0 + r, NN - 1);
        float4 v = ((const float4*)feat)[rr * 32 + u];
        unsigned p0 = pk_f16(v.x, v.y);
        unsigned p1 = pk_f16(v.z, v.w);
        *(unsigned*)&As[r * 136 + u * 4]     = p0;
        *(unsigned*)&As[r * 136 + u * 4 + 2] = p1;
        *(uint2*)&featbf[rr * 128 + u * 4] = make_uint2(p0, p1);   // write fp16 feat table
    }
    __syncthreads();
    int lane = tid & 63, w = tid >> 6;
    int quad = lane >> 4, l15 = lane & 15;
    #pragma unroll 1
    for (int gy = 0; gy < 2; ++gy) {
        const unsigned short* B = wnodebf + (gy + 2) * 128 * 128;
        const float* bias = gy == 0 ? pool_b : pool2_b;
        f32x4 acc[8] = {};
        #pragma unroll 1
        for (int ks = 0; ks < 4; ++ks) {
            f16x8 a = *(const f16x8*)&As[(w * 16 + l15) * 136 + ks * 32 + quad * 8];
            #pragma unroll
            for (int t = 0; t < 8; ++t) {
                f16x8 b = *(const f16x8*)&B[(t * 16 + l15) * 128 + ks * 32 + quad * 8];
                acc[t] = __builtin_amdgcn_mfma_f32_16x16x32_f16(a, b, acc[t], 0, 0, 0);
            }
        }
        #pragma unroll
        for (int reg = 0; reg < 4; ++reg) {
            int lr = w * 16 + quad * 4 + reg;
            #pragma unroll
            for (int t = 0; t < 8; ++t) {
                int col = t * 16 + l15;
                // interleaved layout: col c of group gy -> (c>>1)*4 + (c&1) + gy*2
                Hs[lr * 264 + ((col >> 1) << 2) + (col & 1) + gy * 2] =
                    f2h(gelu_f(acc[t][reg] + bias[col]));
            }
        }
    }
    __syncthreads();
    #pragma unroll
    for (int it = 0; it < 8; ++it) {          // 64 rows x 32 8-ushort chunks, 16B stores
        int idx = tid + it * 256;
        int r = idx >> 5, u = idx & 31;
        int row = row0 + r;
        if (row < NN)
            *(uint4*)&hbf[row * 256 + u * 8] = *(const uint4*)&Hs[r * 264 + u * 8];
    }
}

// ---------------- edge GEMM: fused K=384 [fs*fd | fs | fd] @ B (fp16), B LDS-staged dbuf
// (48 KB, 3 blocks/CU — register-bound occupancy, R8-proven), T14 split, A prefetch d2 ----
__global__ __launch_bounds__(256, 3) void gemm_edge(const unsigned short* __restrict__ featbf,
                                                    const unsigned short* __restrict__ wedgebf,
                                                    float* __restrict__ ws) {
    __shared__ unsigned short Bs[2][24 * 512];   // 2 x 24 KB (24 fragments x 64 lanes x 8 fp16)
    int tid = threadIdx.x;
    int lane = tid & 63, w = tid >> 6;
    int quad = lane >> 4, l15 = lane & 15;
    int e0 = blockIdx.x * 128;
    const int2* ssrcd = (const int2*)(ws + OFF_SSRCD);
    int base = e0 + w * 32 + l15;                // wave handles edges [e0+w*32, +32)
    int2 i0 = ssrcd[base];
    int2 i1 = ssrcd[base + 16];
    const unsigned short* p0s = &featbf[i0.x * 128];
    const unsigned short* p0d = &featbf[i0.y * 128];
    const unsigned short* p1s = &featbf[i1.x * 128];
    const unsigned short* p1d = &featbf[i1.y * 128];
    int ko = quad * 8;

    // ---- prologue: A chunks kb0,kb1; B stage kb0 ----
    uint4 ca[2][4];                              // A double-buffer [kb&1][stream]
    ca[0][0] = *(const uint4*)&p0s[ko];
    ca[0][1] = *(const uint4*)&p0d[ko];
    ca[0][2] = *(const uint4*)&p1s[ko];
    ca[0][3] = *(const uint4*)&p1d[ko];
    ca[1][0] = *(const uint4*)&p0s[ko + 32];
    ca[1][1] = *(const uint4*)&p0d[ko + 32];
    ca[1][2] = *(const uint4*)&p1s[ko + 32];
    ca[1][3] = *(const uint4*)&p1d[ko + 32];
    uint4 sb[6];                                 // B staging regs: wave w owns frags ts = w*6..w*6+5
    #pragma unroll
    for (int i = 0; i < 6; ++i) {
        int ts = w * 6 + i;
        sb[i] = *(const uint4*)&wedgebf[(ts * 4 + 0) * 512 + lane * 8];
    }
    #pragma unroll
    for (int i = 0; i < 6; ++i) {
        int ts = w * 6 + i;
        *(uint4*)&Bs[0][ts * 512 + lane * 8] = sb[i];
    }
    __syncthreads();

    f32x4 acc0[8] = {}, acc1[8] = {};
    #pragma unroll
    for (int kb = 0; kb < 4; ++kb) {
        // consume current A chunk into fp16 fragments (before overwrite by prefetch)
        uint4 c0s = ca[kb & 1][0], c0d = ca[kb & 1][1];
        uint4 c1s = ca[kb & 1][2], c1d = ca[kb & 1][3];
        uint4 m0, m1;                            // elementwise fs*fd via v_pk_mul_f16
        m0.x = mulpack_h(c0s.x, c0d.x); m0.y = mulpack_h(c0s.y, c0d.y);
        m0.z = mulpack_h(c0s.z, c0d.z); m0.w = mulpack_h(c0s.w, c0d.w);
        m1.x = mulpack_h(c1s.x, c1d.x); m1.y = mulpack_h(c1s.y, c1d.y);
        m1.z = mulpack_h(c1s.z, c1d.z); m1.w = mulpack_h(c1s.w, c1d.w);
        f16x8 am0 = *(const f16x8*)&m0,  am1 = *(const f16x8*)&m1;
        f16x8 as0 = *(const f16x8*)&c0s, ad0 = *(const f16x8*)&c0d;
        f16x8 as1 = *(const f16x8*)&c1s, ad1 = *(const f16x8*)&c1d;
        // issue A prefetch for kb+2 into the freed slot
        if (kb < 2) {
            int k2 = ko + (kb + 2) * 32;
            ca[kb & 1][0] = *(const uint4*)&p0s[k2];
            ca[kb & 1][1] = *(const uint4*)&p0d[k2];
            ca[kb & 1][2] = *(const uint4*)&p1s[k2];
            ca[kb & 1][3] = *(const uint4*)&p1d[k2];
        }
        // issue B global loads for kb+1 (write to LDS after MFMA phase — T14 split)
        if (kb < 3) {
            #pragma unroll
            for (int i = 0; i < 6; ++i) {
                int ts = w * 6 + i;
                sb[i] = *(const uint4*)&wedgebf[(ts * 4 + kb + 1) * 512 + lane * 8];
            }
        }
        // MFMA phase: B from LDS (ds_read_b128, conflict-free)
        const unsigned short* bb = &Bs[kb & 1][lane * 8];
        #pragma unroll
        for (int t = 0; t < 8; ++t) {
            f16x8 bm = *(const f16x8*)&bb[(t * 3 + 0) * 512];
            f16x8 b1 = *(const f16x8*)&bb[(t * 3 + 1) * 512];
            f16x8 b2 = *(const f16x8*)&bb[(t * 3 + 2) * 512];
            acc0[t] = __builtin_amdgcn_mfma_f32_16x16x32_f16(am0, bm, acc0[t], 0, 0, 0);
            acc1[t] = __builtin_amdgcn_mfma_f32_16x16x32_f16(am1, bm, acc1[t], 0, 0, 0);
            acc0[t] = __builtin_amdgcn_mfma_f32_16x16x32_f16(as0, b1, acc0[t], 0, 0, 0);
            acc1[t] = __builtin_amdgcn_mfma_f32_16x16x32_f16(as1, b1, acc1[t], 0, 0, 0);
            acc0[t] = __builtin_amdgcn_mfma_f32_16x16x32_f16(ad0, b2, acc0[t], 0, 0, 0);
            acc1[t] = __builtin_amdgcn_mfma_f32_16x16x32_f16(ad1, b2, acc1[t], 0, 0, 0);
        }
        // write-late: staged B -> LDS buf for kb+1, then barrier
        if (kb < 3) {
            #pragma unroll
            for (int i = 0; i < 6; ++i) {
                int ts = w * 6 + i;
                *(uint4*)&Bs[(kb + 1) & 1][ts * 512 + lane * 8] = sb[i];
            }
            __syncthreads();
        }
    }

    // epilogue: e = leaky(sum_col gelu(acc + be) * waout + b_aout)
    const float* waout = ws + OFF_WAOUT;
    const float* be = ws + OFF_BE;
    float b_aout = ws[OFF_BAOUT];
    float* e_out = ws + OFF_SEV;
    float wv[8], bv[8];
    #pragma unroll
    for (int t = 0; t < 8; ++t) { wv[t] = waout[t * 16 + l15]; bv[t] = be[t * 16 + l15]; }
    #pragma unroll
    for (int g = 0; g < 2; ++g) {
        #pragma unroll
        for (int reg = 0; reg < 4; ++reg) {
            int r = w * 32 + g * 16 + quad * 4 + reg;
            float partial = 0.0f;
            #pragma unroll
            for (int t = 0; t < 8; ++t) {
                float v = (g ? acc1[t][reg] : acc0[t][reg]) + bv[t];
                partial += gelu_f(v) * wv[t];
            }
            partial += __shfl_xor(partial, 1, 16);
            partial += __shfl_xor(partial, 2, 16);
            partial += __shfl_xor(partial, 4, 16);
            partial += __shfl_xor(partial, 8, 16);
            if (l15 == 0) e_out[e0 + r] = leaky_f(partial + b_aout);
        }
    }
}

// ---------------- fused final GEMM (K=384) + 2 residual MLP layers -> out f32 (single pass) ----
__global__ __launch_bounds__(256) void gemm_final_mlp(const unsigned short* __restrict__ neighbf,
                                                      const unsigned short* __restrict__ featbf,
                                                      const unsigned short* __restrict__ wfinbf,
                                                      const unsigned short* __restrict__ wmlpbf,
                                                      const float* __restrict__ mlp_b,
                                                      float* __restrict__ out,
                                                      const float* __restrict__ ws) {
    __shared__ unsigned short As[64 * 392];   // stage1: 64x384 (+8 pad); reused as 64x136 for MLP
    __shared__ float bfin_s[128];
    int tid = threadIdx.x;
    int row0 = blockIdx.x * 64;
    if (tid < 128) bfin_s[tid] = ws[OFF_BFIN + tid];
    #pragma unroll
    for (int rg = 0; rg < 3; ++rg) {
        #pragma unroll
        for (int it = 0; it < 4; ++it) {
            int idx = tid + it * 256;
            int r = idx >> 4, u = idx & 15;
            int rr = min(row0 + r, NN - 1);
            const unsigned short* sp = (rg == 0) ? &neighbf[rr * 256 + u * 8]
                                     : (rg == 1) ? &neighbf[rr * 256 + 128 + u * 8]
                                                 : &featbf[rr * 128 + u * 8];
            *(uint4*)&As[r * 392 + rg * 128 + u * 8] = *(const uint4*)sp;
        }
    }
    __syncthreads();
    int lane = tid & 63, w = tid >> 6;
    int quad = lane >> 4, l15 = lane & 15;
    f32x4 rst[8] = {};
    #pragma unroll 1
    for (int ks = 0; ks < 12; ++ks) {
        f16x8 a = *(const f16x8*)&As[(w * 16 + l15) * 392 + ks * 32 + quad * 8];
        #pragma unroll
        for (int t = 0; t < 8; ++t) {
            f16x8 b = *(const f16x8*)&wfinbf[(t * 16 + l15) * 384 + ks * 32 + quad * 8];
            rst[t] = __builtin_amdgcn_mfma_f32_16x16x32_f16(a, b, rst[t], 0, 0, 0);
        }
    }
    #pragma unroll
    for (int t = 0; t < 8; ++t) {
        float bf = bfin_s[t * 16 + l15];
        #pragma unroll
        for (int reg = 0; reg < 4; ++reg) rst[t][reg] += bf;
    }
    // two residual MLP layers, all in-block (no global round trip)
    #pragma unroll 1
    for (int layer = 0; layer < 2; ++layer) {
        __syncthreads();                       // prior As reads complete before overwrite
        #pragma unroll
        for (int t = 0; t < 8; ++t) {
            #pragma unroll
            for (int reg = 0; reg < 4; ++reg) {
                int row = w * 16 + quad * 4 + reg;
                As[row * 136 + t * 16 + l15] = f2h(gelu_f(rst[t][reg]));
            }
        }
        __syncthreads();
        const unsigned short* wB = wmlpbf + layer * 16384;
        f32x4 acc[8] = {};
        #pragma unroll 1
        for (int ks = 0; ks < 4; ++ks) {
            f16x8 a = *(const f16x8*)&As[(w * 16 + l15) * 136 + ks * 32 + quad * 8];
            #pragma unroll
            for (int t = 0; t < 8; ++t) {
                f16x8 b = *(const f16x8*)&wB[(t * 16 + l15) * 128 + ks * 32 + quad * 8];
                acc[t] = __builtin_amdgcn_mfma_f32_16x16x32_f16(a, b, acc[t], 0, 0, 0);
            }
        }
        #pragma unroll
        for (int t = 0; t < 8; ++t) {
            float bias = mlp_b[layer * 128 + t * 16 + l15];
            #pragma unroll
            for (int reg = 0; reg < 4; ++reg) rst[t][reg] += acc[t][reg] + bias;
        }
    }
    #pragma unroll
    for (int reg = 0; reg < 4; ++reg) {
        int row = row0 + w * 16 + quad * 4 + reg;
        if (row >= NN) continue;
        #pragma unroll
        for (int t = 0; t < 8; ++t) {
            out[row * 128 + t * 16 + l15] = rst[t][reg];
        }
    }
}

// ---------------- host launch ----------------
extern "C" void kernel_launch(void* const* d_in, const int* in_sizes, int n_in,
                              void* d_out, int out_size, void* d_ws, size_t ws_size,
                              hipStream_t stream) {
    const float* feat = (const float*)d_in[0];
    WnormArgs wa;
    wa.asrc_v = (const float*)d_in[1];  wa.asrc_g = (const float*)d_in[2];  wa.asrc_b = (const float*)d_in[3];
    wa.adst_v = (const float*)d_in[4];  wa.adst_g = (const float*)d_in[5];  wa.adst_b = (const float*)d_in[6];
    wa.asub_v = (const float*)d_in[7];  wa.asub_g = (const float*)d_in[8];  wa.asub_b = (const float*)d_in[9];
    wa.amul_v = (const float*)d_in[10]; wa.amul_g = (const float*)d_in[11]; wa.amul_b = (const float*)d_in[12];
    wa.aout_v = (const float*)d_in[13]; wa.aout_g = (const float*)d_in[14]; wa.aout_b = (const float*)d_in[15];
    wa.pool_v = (const float*)d_in[16]; wa.pool_g = (const float*)d_in[17]; wa.pool_b = (const float*)d_in[18];
    wa.pool2_v= (const float*)d_in[19]; wa.pool2_g= (const float*)d_in[20]; wa.pool2_b= (const float*)d_in[21];
    wa.self_v = (const float*)d_in[22]; wa.self_g = (const float*)d_in[23]; wa.self_b = (const float*)d_in[24];
    wa.neigh_v= (const float*)d_in[25]; wa.neigh_g= (const float*)d_in[26]; wa.neigh_b= (const float*)d_in[27];
    wa.neigh2_v=(const float*)d_in[28]; wa.neigh2_g=(const float*)d_in[29]; wa.neigh2_b=(const float*)d_in[30];
    wa.mlp_v  = (const float*)d_in[31]; wa.mlp_g  = (const float*)d_in[32]; wa.mlp_b  = (const float*)d_in[33];
    const int* src = (const int*)d_in[34];
    const int* dst = (const int*)d_in[35];
    float* out = (float*)d_out;
    float* ws = (float*)d_ws;
    wa.ws = ws;
    unsigned short* featbf  = (unsigned short*)(ws + OFF_FEATBF);
    unsigned short* hbf     = (unsigned short*)(ws + OFF_HBF);
    unsigned short* neighbf = (unsigned short*)(ws + OFF_NEIGHBF);
    unsigned short* wnodebf = (unsigned short*)(ws + OFF_WNODEBF);
    unsigned short* wfinbf  = (unsigned short*)(ws + OFF_WFINBF);
    unsigned short* wmlpbf  = (unsigned short*)(ws + OFF_WMLPBF);
    unsigned short* wedgebf = (unsigned short*)(ws + OFF_WEDGEBF);

    // 1) normalized weights + fused bias vectors (+ hist zero)
    wnorm_kernel<<<dim3(1281), dim3(128), 0, stream>>>(wa);
    // 2) weight tables -> fp16 (+ fused dst histogram)
    convert_weights_kernel<<<dim3(768), dim3(256), 0, stream>>>(dst, ws);
    // 3) CSR-by-dst (two-level parallel scan; tops merged into add)
    scan_blocks_kernel<<<dim3(SCAN_NB), dim3(256), 0, stream>>>(ws);
    scan_add_kernel<<<dim3(SCAN_NB), dim3(256), 0, stream>>>(ws);
    scatteridx_kernel<<<dim3((EE + 255) / 256), dim3(256), 0, stream>>>(src, dst, ws);
    // 4) node GEMM (MFMA fp16): converts feat->fp16, computes h/h2, vectorized hbf store
    gemm_node_mfma<<<dim3(782), dim3(256), 0, stream>>>(feat, wa.pool_b, wa.pool2_b, featbf, hbf, wnodebf);
    // 5) edge GEMM (fused K=384, dbuf LDS B, 3 waves/SIMD — R8-proven) -> sev
    gemm_edge<<<dim3(EE / 128), dim3(256), 0, stream>>>(featbf, wedgebf, ws);
    // 6) segmented reduce -> neighbf (50k-wave parallel, 8B fused h/h2 loads)
    segreduce_kernel<<<dim3(NN / 4), dim3(256), 0, stream>>>(ws);
    // 7) fused final GEMM + 2 MLP layers -> out (single pass, no global round trips)
    gemm_final_mlp<<<dim3(782), dim3(256), 0, stream>>>(neighbf, featbf, wfinbf, wmlpbf, wa.mlp_b, out, ws);
}